// Round 1
// baseline (410.757 us; speedup 1.0000x reference)
//
#include <hip/hip_runtime.h>
#include <math.h>

#define NVARS 14
#define EDIM 32
#define VMIX 3
#define DCH 16
#define KSTATES 16384
#define BATCH 32
#define SPB 8  // states per block

// ws layout (floats):
//   contrib: [V][NV][2][288]  offset 0      size 24192
//   base:    [V][288]         offset 24192  size 864
//   delta:   [V][NV][288]     offset 25056  size 12096
#define WS_BASE 24192
#define WS_DELTA 25056

// ---------------- precompute 1: contrib[v][n][c][j] ----------------
// contrib = (emb[n][c] @ lin_w[v, n-block]) @ w1-stamp   (j = o*9+pos, o<32)
__global__ __launch_bounds__(64) void pre1_kernel(const float* __restrict__ emb,
                                                  const float* __restrict__ lin_w,
                                                  const float* __restrict__ w1,
                                                  float* __restrict__ ws) {
    int blk = blockIdx.x;            // v*28 + n*2 + c
    int v = blk / 28;
    int rem = blk % 28;
    int n = rem >> 1;
    int c = rem & 1;
    int tid = threadIdx.x;           // 64 threads

    __shared__ float sT[64];
    // t[i] = sum_e emb[n][c][e] * lin_w[v][n*32+e][i]
    {
        const float* e = emb + (n * 2 + c) * EDIM;
        const float* lw = lin_w + ((size_t)v * 448 + n * 32) * 64 + tid;
        float acc = 0.f;
        #pragma unroll
        for (int eidx = 0; eidx < 32; ++eidx)
            acc = fmaf(e[eidx], lw[eidx * 64], acc);
        sT[tid] = acc;
    }
    __syncthreads();
    // contrib[j] = sum_i t[i] * w1[v][i][j]   (w1 flattened (V,64,288))
    float* out = ws + ((size_t)(v * NVARS + n) * 2 + c) * 288;
    const float* w1v = w1 + (size_t)v * 64 * 288;
    for (int j = tid; j < 288; j += 64) {
        float acc = 0.f;
        for (int i = 0; i < 64; ++i)
            acc = fmaf(sT[i], w1v[i * 288 + j], acc);
        out[j] = acc;
    }
}

// ---------------- precompute 2: base & delta ----------------
__global__ __launch_bounds__(256) void pre2_kernel(const float* __restrict__ lin_b,
                                                   const float* __restrict__ b1,
                                                   const float* __restrict__ w1,
                                                   float* __restrict__ ws) {
    int v = blockIdx.x;
    int tid = threadIdx.x;
    const float* w1v = w1 + (size_t)v * 64 * 288;
    const float* lbv = lin_b + v * 64;
    const float* contrib = ws + (size_t)v * NVARS * 2 * 288;
    float* base = ws + WS_BASE + v * 288;
    float* delta = ws + WS_DELTA + (size_t)v * NVARS * 288;
    for (int j = tid; j < 288; j += 256) {
        int o = j / 9;
        float acc = b1[v * 32 + o];
        for (int i = 0; i < 64; ++i)
            acc = fmaf(lbv[i], w1v[i * 288 + j], acc);
        for (int n = 0; n < NVARS; ++n) {
            float c0 = contrib[(n * 2 + 0) * 288 + j];
            float c1 = contrib[(n * 2 + 1) * 288 + j];
            acc += c0;
            delta[n * 288 + j] = c1 - c0;
        }
        base[j] = acc;
    }
}

// ---------------- main kernel ----------------
__global__ __launch_bounds__(256) void emission_main(const float* __restrict__ x,
                                                     const float* __restrict__ w2,
                                                     const float* __restrict__ b2,
                                                     const float* __restrict__ w3,
                                                     const float* __restrict__ b3,
                                                     const float* __restrict__ ws,
                                                     float* __restrict__ out) {
    int bid = blockIdx.x;
    int v = bid % 3;
    int chunk = bid / 3;         // states [chunk*8, chunk*8+8)
    int tid = threadIdx.x;

    __shared__ float sW2[4608];        // [i<32][o<16][tap<9]
    __shared__ float sW3[144];         // [i<16][tap<9]
    __shared__ float sX[BATCH * 49];   // [b][p]
    __shared__ float sCommon[288];
    __shared__ float sH1[SPB * 289];   // [s][i*9+pos], stride 289 (bank pad)
    __shared__ float sH2[SPB * 400];   // [s][o*25 + pos]
    __shared__ float sM[SPB * 49];     // [s][p]

    // stage 0: stage weights / x
    {
        const float* w2v = w2 + v * 4608;  // same layout: i*144 + o*9 + tap
        for (int t = tid; t < 4608; t += 256) sW2[t] = w2v[t];
        const float* w3v = w3 + v * 144;
        if (tid < 144) sW3[tid] = w3v[tid];
        for (int t = tid; t < BATCH * 49; t += 256) {
            int b = t / 49;
            int p = t - b * 49;
            sX[t] = x[(size_t)(b * 3 + v) * 49 + p];
        }
    }
    // stage 1a: common part of h1pre (top 11 bits, block-uniform)
    const float* base = ws + WS_BASE + v * 288;
    const float* delta = ws + WS_DELTA + (size_t)v * NVARS * 288;
    for (int j = tid; j < 288; j += 256) {
        float a = base[j];
        #pragma unroll
        for (int n = 0; n < 11; ++n)
            if ((chunk >> (10 - n)) & 1) a += delta[n * 288 + j];
        sCommon[j] = a;
    }
    __syncthreads();
    // stage 1b: per-state low 3 bits + ELU
    {
        const float* d11 = delta + 11 * 288;
        const float* d12 = delta + 12 * 288;
        const float* d13 = delta + 13 * 288;
        for (int t = tid; t < SPB * 288; t += 256) {
            int s = t / 288;
            int j = t - s * 288;
            float pre = sCommon[j];
            pre = fmaf((float)((s >> 2) & 1), d11[j], pre);
            pre = fmaf((float)((s >> 1) & 1), d12[j], pre);
            pre = fmaf((float)(s & 1), d13[j], pre);
            sH1[s * 289 + j] = pre > 0.f ? pre : expm1f(pre);
        }
    }
    __syncthreads();
    // stage 2: conv2 (3x3 -> 5x5, 32->16 ch), exact-tap scatter form.
    // thread = (s, o, half); half splits input channels 0..15 / 16..31.
    {
        int s = tid >> 5;
        int o = (tid >> 1) & 15;
        int half = tid & 1;
        float acc[25];
        #pragma unroll
        for (int p = 0; p < 25; ++p) acc[p] = 0.f;
        const float* h1s = sH1 + s * 289;
        int i0 = half * 16;
        for (int i = i0; i < i0 + 16; ++i) {
            float h[9], w[9];
            #pragma unroll
            for (int p = 0; p < 9; ++p) h[p] = h1s[i * 9 + p];
            #pragma unroll
            for (int p = 0; p < 9; ++p) w[p] = sW2[i * 144 + o * 9 + p];
            #pragma unroll
            for (int y = 0; y < 3; ++y)
                #pragma unroll
                for (int xx = 0; xx < 3; ++xx)
                    #pragma unroll
                    for (int a = 0; a < 3; ++a)
                        #pragma unroll
                        for (int bb = 0; bb < 3; ++bb)
                            acc[(y + a) * 5 + (xx + bb)] =
                                fmaf(h[y * 3 + xx], w[a * 3 + bb],
                                     acc[(y + a) * 5 + (xx + bb)]);
        }
        float* h2so = sH2 + s * 400 + o * 25;
        if (half == 1) {
            #pragma unroll
            for (int p = 0; p < 25; ++p) h2so[p] = acc[p];
        }
        __syncthreads();
        if (half == 0) {
            float bo = b2[v * 16 + o];
            #pragma unroll
            for (int p = 0; p < 25; ++p) {
                float val = acc[p] + h2so[p] + bo;
                h2so[p] = val > 0.f ? val : expm1f(val);
            }
        }
    }
    __syncthreads();
    // stage 3: conv3 (5x5 -> 7x7, 16->1 ch)
    {
        float b3v = b3[v];
        for (int t = tid; t < SPB * 49; t += 256) {
            int s = t / 49;
            int p = t - s * 49;
            int Y = p / 7, X = p - Y * 7;
            float acc = b3v;
            const float* h2s = sH2 + s * 400;
            for (int i = 0; i < 16; ++i) {
                #pragma unroll
                for (int a = 0; a < 3; ++a) {
                    int y = Y - a;
                    if (y < 0 || y > 4) continue;
                    #pragma unroll
                    for (int bb = 0; bb < 3; ++bb) {
                        int xx = X - bb;
                        if (xx < 0 || xx > 4) continue;
                        acc = fmaf(h2s[i * 25 + y * 5 + xx],
                                   sW3[i * 9 + a * 3 + bb], acc);
                    }
                }
            }
            sM[s * 49 + p] = acc;
        }
    }
    __syncthreads();
    // stage 4: -(1/2) * sum_p (m - x_b)^2, thread = (s, b)
    {
        int s = tid >> 5;
        int b = tid & 31;
        const float* ms = sM + s * 49;
        const float* xb = sX + b * 49;
        float acc = 0.f;
        #pragma unroll
        for (int p = 0; p < 49; ++p) {
            float d = ms[p] - xb[p];
            acc = fmaf(d, d, acc);
        }
        int k = chunk * SPB + s;
        out[(size_t)b * (KSTATES * 3) + (size_t)k * 3 + v] = -0.5f * acc;
    }
}

extern "C" void kernel_launch(void* const* d_in, const int* in_sizes, int n_in,
                              void* d_out, int out_size, void* d_ws, size_t ws_size,
                              hipStream_t stream) {
    const float* x    = (const float*)d_in[0];   // (32,3,7,7)
    const float* emb  = (const float*)d_in[1];   // (14,2,32)
    const float* linw = (const float*)d_in[2];   // (3,448,64)
    const float* linb = (const float*)d_in[3];   // (3,64)
    const float* w1   = (const float*)d_in[4];   // (3,64,32,3,3)
    const float* b1   = (const float*)d_in[5];   // (3,32)
    const float* w2   = (const float*)d_in[6];   // (3,32,16,3,3)
    const float* b2   = (const float*)d_in[7];   // (3,16)
    const float* w3   = (const float*)d_in[8];   // (3,16,1,3,3)
    const float* b3   = (const float*)d_in[9];   // (3,1)
    float* out = (float*)d_out;
    float* ws = (float*)d_ws;

    pre1_kernel<<<VMIX * NVARS * 2, 64, 0, stream>>>(emb, linw, w1, ws);
    pre2_kernel<<<VMIX, 256, 0, stream>>>(linb, b1, w1, ws);
    emission_main<<<(KSTATES / SPB) * VMIX, 256, 0, stream>>>(x, w2, b2, w3, b3, ws, out);
}

// Round 2
// 157.483 us; speedup vs baseline: 2.6083x; 2.6083x over previous
//
#include <hip/hip_runtime.h>
#include <math.h>

#define NVARS 14
#define EDIM 32
#define VMIX 3
#define KSTATES 16384
#define BATCH 32

// ws float region (fp32):
//   contrib: [V][NV][2][288]  float offset 0      (24192)
//   base:    [V][288]         float offset 24192  (864)
//   delta:   [V][NV][288]     float offset 25056  (12096)
#define WS_BASE 24192
#define WS_DELTA 25056
// bf16 swizzled-fragment regions (byte offsets, contiguous after fp32 region):
#define WS_DSWZ_B  148608                      // [V][18][64][8] bf16 = 55296 B
#define WS_W2SWZ_B (WS_DSWZ_B + 55296)         // [V][9][26][64][8] = 718848 B
#define WS_W3SWZ_B (WS_W2SWZ_B + 718848)       // [V][13][4][64][8] = 79872 B

typedef __attribute__((ext_vector_type(8))) short bf16x8;
typedef __attribute__((ext_vector_type(4))) float f32x4;

static __device__ inline unsigned short f2bf(float f) {
    unsigned u = __float_as_uint(f);
    u += 0x7FFFu + ((u >> 16) & 1u);   // RNE
    return (unsigned short)(u >> 16);
}
static __device__ inline float elu(float x) {
    return x > 0.f ? x : (__expf(x) - 1.f);
}

// ---------------- preA: contrib[v][n][c][j] ----------------
__global__ __launch_bounds__(256) void preA_kernel(const float* __restrict__ emb,
                                                   const float* __restrict__ lin_w,
                                                   const float* __restrict__ w1,
                                                   float* __restrict__ ws) {
    int blk = blockIdx.x;            // v*28 + n*2 + c
    int v = blk / 28;
    int rem = blk % 28;
    int n = rem >> 1;
    int c = rem & 1;
    int tid = threadIdx.x;

    __shared__ float sT[64];
    if (tid < 64) {
        const float* e = emb + (n * 2 + c) * EDIM;
        const float* lw = lin_w + ((size_t)v * 448 + n * 32) * 64 + tid;
        float acc = 0.f;
        #pragma unroll
        for (int eidx = 0; eidx < 32; ++eidx)
            acc = fmaf(e[eidx], lw[eidx * 64], acc);
        sT[tid] = acc;
    }
    __syncthreads();
    float* outp = ws + ((size_t)(v * NVARS + n) * 2 + c) * 288;
    const float* w1v = w1 + (size_t)v * 64 * 288;
    for (int j = tid; j < 288; j += 256) {
        float acc = 0.f;
        for (int i = 0; i < 64; ++i)
            acc = fmaf(sT[i], w1v[i * 288 + j], acc);
        outp[j] = acc;
    }
}

// ---------------- preB: base & delta ----------------
__global__ __launch_bounds__(320) void preB_kernel(const float* __restrict__ lin_b,
                                                   const float* __restrict__ b1,
                                                   const float* __restrict__ w1,
                                                   float* __restrict__ ws) {
    int v = blockIdx.x;
    int j = threadIdx.x;
    if (j >= 288) return;
    const float* w1v = w1 + (size_t)v * 64 * 288;
    const float* lbv = lin_b + v * 64;
    const float* contrib = ws + (size_t)v * NVARS * 2 * 288;
    float* base = ws + WS_BASE + v * 288;
    float* delta = ws + WS_DELTA + (size_t)v * NVARS * 288;
    int o = j / 9;
    float acc = b1[v * 32 + o];
    for (int i = 0; i < 64; ++i)
        acc = fmaf(lbv[i], w1v[i * 288 + j], acc);
    for (int n = 0; n < NVARS; ++n) {
        float c0 = contrib[(n * 2 + 0) * 288 + j];
        float c1 = contrib[(n * 2 + 1) * 288 + j];
        acc += c0;
        delta[n * 288 + j] = c1 - c0;
    }
    base[j] = acc;
}

// ---------------- preC: build bf16 MFMA-fragment-swizzled B matrices ----------------
// group g (16 B each): 0..3455 Dmat | 3456..48383 W2eff | 48384..58367 W3eff
__global__ __launch_bounds__(256) void preC_kernel(const float* __restrict__ w2,
                                                   const float* __restrict__ w3,
                                                   float* __restrict__ ws) {
    int g = blockIdx.x * 256 + threadIdx.x;   // 58368 total
    const float* wsf = ws;
    char* wsb = (char*)ws;
    bf16x8 o8;
    if (g < 3456) {
        int v = g / 1152;
        int r = g % 1152;
        int nt = r / 64, l = r % 64;
        int n = nt * 16 + (l & 15);
        int kbase = ((l >> 4) & 3) * 8;
        const float* base = wsf + WS_BASE + v * 288;
        const float* delta = wsf + WS_DELTA + (size_t)v * NVARS * 288;
        #pragma unroll
        for (int j = 0; j < 8; ++j) {
            int k = kbase + j;
            float val = 0.f;
            if (k < 14) val = delta[k * 288 + n];
            else if (k == 14) val = base[n];
            o8[j] = (short)f2bf(val);
        }
    } else if (g < 48384) {
        int h = g - 3456;
        int v = h / 14976;
        int r = h % 14976;
        int kt = r / 1664;
        int r2 = r % 1664;
        int nt = r2 / 64, l = r2 % 64;
        int n = nt * 16 + (l & 15);
        int kbase = kt * 32 + ((l >> 4) & 3) * 8;
        #pragma unroll
        for (int j = 0; j < 8; ++j) {
            int k = kbase + j;           // k < 288
            float val = 0.f;
            if (n < 400) {
                int i = k / 9, p = k % 9;
                int py = p / 3, px = p % 3;
                int o = n / 25, q = n % 25;
                int qy = q / 5, qx = q % 5;
                int ty = qy - py, tx = qx - px;
                if (ty >= 0 && ty < 3 && tx >= 0 && tx < 3)
                    val = w2[((size_t)(v * 32 + i) * 16 + o) * 9 + ty * 3 + tx];
            }
            o8[j] = (short)f2bf(val);
        }
    } else {
        int h = g - 48384;
        int v = h / 3328;
        int r = h % 3328;
        int kt = r / 256;
        int r2 = r % 256;
        int nt = r2 / 64, l = r2 % 64;
        int n = nt * 16 + (l & 15);      // output pixel 0..48 (else pad)
        int kbase = kt * 32 + ((l >> 4) & 3) * 8;
        #pragma unroll
        for (int j = 0; j < 8; ++j) {
            int k = kbase + j;
            float val = 0.f;
            if (k < 400 && n < 49) {
                int o = k / 25, q = k % 25;
                int qy = q / 5, qx = q % 5;
                int py = n / 7, px = n % 7;
                int ty = py - qy, tx = px - qx;
                if (ty >= 0 && ty < 3 && tx >= 0 && tx < 3)
                    val = w3[(size_t)(v * 16 + o) * 9 + ty * 3 + tx];
            }
            o8[j] = (short)f2bf(val);
        }
    }
    *(bf16x8*)(wsb + WS_DSWZ_B + (size_t)g * 16) = o8;
}

// ---------------- main: MFMA decoder + distance ----------------
__global__ __launch_bounds__(256, 2) void emission_main(const float* __restrict__ x,
                                                        const float* __restrict__ b2,
                                                        const float* __restrict__ b3p,
                                                        const float* __restrict__ ws,
                                                        float* __restrict__ out) {
    int bid = blockIdx.x;
    int v = bid >> 8;           // 768 = 3 * 256
    int chunk = bid & 255;      // states [chunk*64, chunk*64+64)
    int tid = threadIdx.x;
    int w = tid >> 6;           // wave 0..3
    int l = tid & 63;
    int quad = l >> 4;
    int lc = l & 15;
    const char* wsb = (const char*)ws;

    // union buffer: sH1 (64x288 bf16=36864B) -> sH2 (64x416=53248B) -> sM (64x72=9216B)
    __shared__ __align__(16) unsigned short uni[26624];
    __shared__ __align__(16) unsigned short sXf[2 * 2 * 64 * 8];  // [mt][kt][lane][8]
    __shared__ float sMsq[64];
    __shared__ float sXsq[32];
    __shared__ float sB2[16];

    // ---------- P0: small LDS prep ----------
    if (tid < 16) sB2[tid] = b2[v * 16 + tid];
    if (tid < 64) sMsq[tid] = 0.f;
    if (tid >= 64 && tid < 96) {
        int b = tid - 64;
        const float* xb = x + (size_t)(b * 3 + v) * 49;
        float s = 0.f;
        #pragma unroll
        for (int p = 0; p < 49; ++p) s = fmaf(xb[p], xb[p], s);
        sXsq[b] = s;
    }
    for (int t = tid; t < 2048; t += 256) {   // cross-term A-frags (X in bf16)
        int mt = t >> 10;
        int kt = (t >> 9) & 1;
        int lane = (t >> 3) & 63;
        int j = t & 7;
        int b = mt * 16 + (lane & 15);
        int p = kt * 32 + ((lane >> 4) & 3) * 8 + j;
        unsigned short val = 0;
        if (p < 49) val = f2bf(x[(size_t)(b * 3 + v) * 49 + p]);
        sXf[t] = val;
    }

    // ---------- P0b: H1 = ELU(bits @ Dmat), each wave its own m-tile ----------
    {
        int sg = chunk * 64 + w * 16 + lc;
        bf16x8 abits;
        #pragma unroll
        for (int j = 0; j < 8; ++j) {
            int k = quad * 8 + j;
            unsigned short u = 0;
            if (k < 14) u = ((sg >> (13 - k)) & 1) ? 0x3F80 : 0;
            else if (k == 14) u = 0x3F80;
            abits[j] = (short)u;
        }
        const bf16x8* dsw = (const bf16x8*)(wsb + WS_DSWZ_B) + (size_t)v * 18 * 64;
        for (int nt = 0; nt < 18; ++nt) {
            bf16x8 bfrag = dsw[nt * 64 + l];
            f32x4 d = {0.f, 0.f, 0.f, 0.f};
            d = __builtin_amdgcn_mfma_f32_16x16x32_bf16(abits, bfrag, d, 0, 0, 0);
            #pragma unroll
            for (int r = 0; r < 4; ++r)
                uni[(w * 16 + quad * 4 + r) * 288 + nt * 16 + lc] = f2bf(elu(d[r]));
        }
    }
    __syncthreads();

    // ---------- P1: conv2 GEMM  H2pre(64x416) = H1(64x288) @ W2eff ----------
    int ncnt = (w < 2) ? 7 : 6;
    int n0 = (w < 2) ? 7 * w : 14 + 6 * (w - 2);
    f32x4 acc[4][7];
    #pragma unroll
    for (int mt = 0; mt < 4; ++mt)
        #pragma unroll
        for (int j = 0; j < 7; ++j)
            acc[mt][j] = (f32x4){0.f, 0.f, 0.f, 0.f};
    {
        const bf16x8* w2f = (const bf16x8*)(wsb + WS_W2SWZ_B) + (size_t)v * 9 * 26 * 64;
        for (int kt = 0; kt < 9; ++kt) {
            bf16x8 a[4];
            #pragma unroll
            for (int mt = 0; mt < 4; ++mt)
                a[mt] = *(const bf16x8*)&uni[(mt * 16 + lc) * 288 + kt * 32 + quad * 8];
            bf16x8 bfr[7];
            #pragma unroll
            for (int j = 0; j < 7; ++j)
                if (j < ncnt) bfr[j] = w2f[(kt * 26 + n0 + j) * 64 + l];
            #pragma unroll
            for (int j = 0; j < 7; ++j)
                if (j < ncnt)
                    #pragma unroll
                    for (int mt = 0; mt < 4; ++mt)
                        acc[mt][j] = __builtin_amdgcn_mfma_f32_16x16x32_bf16(a[mt], bfr[j], acc[mt][j], 0, 0, 0);
        }
    }
    __syncthreads();   // all H1 reads done before uni is reused as sH2

    // ---------- P2: bias + ELU + bf16 -> sH2[s][416] ----------
    #pragma unroll
    for (int j = 0; j < 7; ++j) {
        if (j < ncnt) {
            int nt = n0 + j;
            int n = nt * 16 + lc;
            #pragma unroll
            for (int mt = 0; mt < 4; ++mt) {
                #pragma unroll
                for (int r = 0; r < 4; ++r) {
                    float val = 0.f;
                    if (n < 400) {
                        int o = n / 25;
                        val = elu(acc[mt][j][r] + sB2[o]);
                    }
                    uni[(mt * 16 + quad * 4 + r) * 416 + n] = f2bf(val);
                }
            }
        }
    }
    __syncthreads();

    // ---------- P3: conv3 GEMM  m(64x64) = H2(64x416) @ W3eff ----------
    f32x4 acc2[4];
    #pragma unroll
    for (int mt = 0; mt < 4; ++mt) acc2[mt] = (f32x4){0.f, 0.f, 0.f, 0.f};
    {
        const bf16x8* w3f = (const bf16x8*)(wsb + WS_W3SWZ_B) + (size_t)v * 13 * 4 * 64;
        for (int kt = 0; kt < 13; ++kt) {
            bf16x8 a[4];
            #pragma unroll
            for (int mt = 0; mt < 4; ++mt)
                a[mt] = *(const bf16x8*)&uni[(mt * 16 + lc) * 416 + kt * 32 + quad * 8];
            bf16x8 bfr = w3f[(kt * 4 + w) * 64 + l];
            #pragma unroll
            for (int mt = 0; mt < 4; ++mt)
                acc2[mt] = __builtin_amdgcn_mfma_f32_16x16x32_bf16(a[mt], bfr, acc2[mt], 0, 0, 0);
        }
    }
    // epilogue: means, ||m||^2, stash m for cross-term
    float b3v = b3p[v];
    float mvals[4][4];
    int p = w * 16 + lc;
    #pragma unroll
    for (int mt = 0; mt < 4; ++mt) {
        #pragma unroll
        for (int r = 0; r < 4; ++r) {
            float m = (p < 49) ? (acc2[mt][r] + b3v) : 0.f;
            mvals[mt][r] = m;
            float sq = m * m;
            sq += __shfl_xor(sq, 1, 64);
            sq += __shfl_xor(sq, 2, 64);
            sq += __shfl_xor(sq, 4, 64);
            sq += __shfl_xor(sq, 8, 64);
            if (lc == 0) atomicAdd(&sMsq[mt * 16 + quad * 4 + r], sq);
        }
    }
    __syncthreads();   // conv3 reads of uni done before reuse as sM
    #pragma unroll
    for (int mt = 0; mt < 4; ++mt)
        #pragma unroll
        for (int r = 0; r < 4; ++r)
            uni[(mt * 16 + quad * 4 + r) * 72 + p] = f2bf(mvals[mt][r]);
    __syncthreads();

    // ---------- P4: cross = X(32x64p) @ M^T(64p x 64s), then combine & store ----------
    f32x4 acc3[2];
    acc3[0] = (f32x4){0.f, 0.f, 0.f, 0.f};
    acc3[1] = (f32x4){0.f, 0.f, 0.f, 0.f};
    #pragma unroll
    for (int kt = 0; kt < 2; ++kt) {
        bf16x8 bm = *(const bf16x8*)&uni[(w * 16 + lc) * 72 + kt * 32 + quad * 8];
        #pragma unroll
        for (int mt = 0; mt < 2; ++mt) {
            bf16x8 a2 = *(const bf16x8*)&sXf[((mt * 2 + kt) * 64 + l) * 8];
            acc3[mt] = __builtin_amdgcn_mfma_f32_16x16x32_bf16(a2, bm, acc3[mt], 0, 0, 0);
        }
    }
    {
        int s = w * 16 + lc;
        float msq = sMsq[s];
        size_t kidx = (size_t)(chunk * 64 + s) * 3 + v;
        #pragma unroll
        for (int mt = 0; mt < 2; ++mt) {
            int bbase = mt * 16 + quad * 4;
            #pragma unroll
            for (int r = 0; r < 4; ++r) {
                int b = bbase + r;
                float val = acc3[mt][r] - 0.5f * (msq + sXsq[b]);
                out[(size_t)b * (KSTATES * 3) + kidx] = val;
            }
        }
    }
}

extern "C" void kernel_launch(void* const* d_in, const int* in_sizes, int n_in,
                              void* d_out, int out_size, void* d_ws, size_t ws_size,
                              hipStream_t stream) {
    const float* x    = (const float*)d_in[0];   // (32,3,7,7)
    const float* emb  = (const float*)d_in[1];   // (14,2,32)
    const float* linw = (const float*)d_in[2];   // (3,448,64)
    const float* linb = (const float*)d_in[3];   // (3,64)
    const float* w1   = (const float*)d_in[4];   // (3,64,32,3,3)
    const float* b1   = (const float*)d_in[5];   // (3,32)
    const float* w2   = (const float*)d_in[6];   // (3,32,16,3,3)
    const float* b2   = (const float*)d_in[7];   // (3,16)
    const float* w3   = (const float*)d_in[8];   // (3,16,1,3,3)
    const float* b3   = (const float*)d_in[9];   // (3,1)
    float* out = (float*)d_out;
    float* ws = (float*)d_ws;

    preA_kernel<<<VMIX * NVARS * 2, 256, 0, stream>>>(emb, linw, w1, ws);
    preB_kernel<<<VMIX, 320, 0, stream>>>(linb, b1, w1, ws);
    preC_kernel<<<228, 256, 0, stream>>>(w2, w3, ws);
    emission_main<<<768, 256, 0, stream>>>(x, b2, b3, ws, out);
}

// Round 3
// 139.619 us; speedup vs baseline: 2.9420x; 1.1279x over previous
//
#include <hip/hip_runtime.h>
#include <math.h>

#define NVARS 14
#define EDIM 32
#define VMIX 3
#define KSTATES 16384
#define BATCH 32

// ws layout:
//   T: [V][NV][2][64] fp32   float offset 0       (5376 floats)
// bf16 swizzled-fragment regions (byte offsets):
#define WS_DSWZ_B  32768                       // [V][18][64][8] bf16 = 55296 B
#define WS_W2SWZ_B (WS_DSWZ_B + 55296)         // [V][9][26][64][8] = 718848 B
#define WS_W3SWZ_B (WS_W2SWZ_B + 718848)       // [V][13][4][64][8] = 79872 B

typedef __attribute__((ext_vector_type(8))) short bf16x8;
typedef __attribute__((ext_vector_type(4))) float f32x4;

static __device__ inline unsigned short f2bf(float f) {
    unsigned u = __float_as_uint(f);
    u += 0x7FFFu + ((u >> 16) & 1u);   // RNE
    return (unsigned short)(u >> 16);
}
static __device__ inline float elu(float x) {
    return x > 0.f ? x : (__expf(x) - 1.f);
}

// ---------------- preA: T table + zero Dmat region + w2/w3 frag swizzles ----------------
// t < 5376: T[vnc][i] = sum_e emb[n][c][e] * lin_w[v][n*32+e][i]
// else g = t-5376 (16B frag groups): g<3456 zero Dmat | g<48384 W2eff | else W3eff
__global__ __launch_bounds__(256) void preA_kernel(const float* __restrict__ emb,
                                                   const float* __restrict__ lin_w,
                                                   const float* __restrict__ w2,
                                                   const float* __restrict__ w3,
                                                   float* __restrict__ ws) {
    int t = blockIdx.x * 256 + threadIdx.x;   // 63744 total
    char* wsb = (char*)ws;
    if (t < 5376) {
        int vnc = t >> 6;
        int i = t & 63;
        int v = vnc / 28;
        int rem = vnc % 28;
        int n = rem >> 1;
        int c = rem & 1;
        const float* e = emb + (n * 2 + c) * EDIM;
        const float* lw = lin_w + ((size_t)v * 448 + n * 32) * 64 + i;
        float acc = 0.f;
        #pragma unroll
        for (int eidx = 0; eidx < 32; ++eidx)
            acc = fmaf(e[eidx], lw[eidx * 64], acc);
        ws[t] = acc;
        return;
    }
    int g = t - 5376;
    if (g >= 58368) return;
    bf16x8 o8;
    if (g < 3456) {
        #pragma unroll
        for (int j = 0; j < 8; ++j) o8[j] = 0;   // Dmat region: zero (preB fills k<15)
    } else if (g < 48384) {
        int h = g - 3456;
        int v = h / 14976;
        int r = h % 14976;
        int kt = r / 1664;
        int r2 = r % 1664;
        int nt = r2 / 64, l = r2 % 64;
        int n = nt * 16 + (l & 15);
        int kbase = kt * 32 + ((l >> 4) & 3) * 8;
        #pragma unroll
        for (int j = 0; j < 8; ++j) {
            int k = kbase + j;           // k < 288
            float val = 0.f;
            if (n < 400) {
                int i = k / 9, p = k % 9;
                int py = p / 3, px = p % 3;
                int o = n / 25, q = n % 25;
                int qy = q / 5, qx = q % 5;
                int ty = qy - py, tx = qx - px;
                if (ty >= 0 && ty < 3 && tx >= 0 && tx < 3)
                    val = w2[((size_t)(v * 32 + i) * 16 + o) * 9 + ty * 3 + tx];
            }
            o8[j] = (short)f2bf(val);
        }
    } else {
        int h = g - 48384;
        int v = h / 3328;
        int r = h % 3328;
        int kt = r / 256;
        int r2 = r % 256;
        int nt = r2 / 64, l = r2 % 64;
        int n = nt * 16 + (l & 15);      // output pixel 0..48 (else pad)
        int kbase = kt * 32 + ((l >> 4) & 3) * 8;
        #pragma unroll
        for (int j = 0; j < 8; ++j) {
            int k = kbase + j;
            float val = 0.f;
            if (k < 400 && n < 49) {
                int o = k / 25, q = k % 25;
                int qy = q / 5, qx = q % 5;
                int py = n / 7, px = n % 7;
                int ty = py - qy, tx = px - qx;
                if (ty >= 0 && ty < 3 && tx >= 0 && tx < 3)
                    val = w3[(size_t)(v * 16 + o) * 9 + ty * 3 + tx];
            }
            o8[j] = (short)f2bf(val);
        }
    }
    *(bf16x8*)(wsb + WS_DSWZ_B + (size_t)g * 16) = o8;
}

// ---------------- preB: Dmat bf16 frags directly (delta rows k<14, base row k=14) ----------------
// thread t -> (v, k, n): val = delta[k][n] (or base[n]); scatter-store one bf16.
__global__ __launch_bounds__(256) void preB_kernel(const float* __restrict__ lin_b,
                                                   const float* __restrict__ b1,
                                                   const float* __restrict__ w1,
                                                   const float* __restrict__ ws_ro,
                                                   float* __restrict__ ws) {
    int t = blockIdx.x * 256 + threadIdx.x;
    if (t >= VMIX * 15 * 288) return;     // 12960
    int v = t / (15 * 288);
    int r = t % (15 * 288);
    int k = r / 288;
    int n = r % 288;                      // lane-consecutive -> coalesced w1 column loads
    const float* w1v = w1 + (size_t)v * 64 * 288;
    const float* Tv = ws_ro + (size_t)v * NVARS * 2 * 64;
    float val;
    if (k < 14) {
        const float* T0 = Tv + (k * 2 + 0) * 64;
        const float* T1 = Tv + (k * 2 + 1) * 64;
        float acc = 0.f;
        for (int i = 0; i < 64; ++i)
            acc = fmaf(T1[i] - T0[i], w1v[i * 288 + n], acc);
        val = acc;
    } else {
        const float* lbv = lin_b + v * 64;
        float acc = b1[v * 32 + n / 9];
        for (int i = 0; i < 64; ++i) {
            float u = lbv[i];
            #pragma unroll
            for (int n2 = 0; n2 < 14; ++n2)
                u += Tv[(n2 * 2 + 0) * 64 + i];
            acc = fmaf(u, w1v[i * 288 + n], acc);
        }
        val = acc;
    }
    int nt = n >> 4;
    int l = (n & 15) | ((k >> 3) << 4);
    int j = k & 7;
    unsigned short* dst = (unsigned short*)((char*)ws + WS_DSWZ_B);
    dst[((size_t)(v * 18 + nt) * 64 + l) * 8 + j] = f2bf(val);
}

// ---------------- main: MFMA decoder + distance ----------------
__global__ __launch_bounds__(256, 3) void emission_main(const float* __restrict__ x,
                                                        const float* __restrict__ b2,
                                                        const float* __restrict__ b3p,
                                                        const float* __restrict__ ws,
                                                        float* __restrict__ out) {
    int bid = blockIdx.x;
    int v = bid >> 8;           // 768 = 3 * 256
    int chunk = bid & 255;      // states [chunk*64, chunk*64+64)
    int tid = threadIdx.x;
    int w = tid >> 6;           // wave 0..3
    int l = tid & 63;
    int quad = l >> 4;
    int lc = l & 15;
    const char* wsb = (const char*)ws;

    // union buffer: sH1 (64x288 bf16=36864B) -> sH2 (64x416=53248B) -> sM (64x72=9216B)
    __shared__ __align__(16) unsigned short uni[26624];
    __shared__ float sMsq[64];
    __shared__ float sXsq[32];
    __shared__ float sB2[16];

    // ---------- P0: small LDS prep ----------
    if (tid < 16) sB2[tid] = b2[v * 16 + tid];
    if (tid < 64) sMsq[tid] = 0.f;
    if (tid >= 64 && tid < 96) {
        int b = tid - 64;
        const float* xb = x + (size_t)(b * 3 + v) * 49;
        float s = 0.f;
        #pragma unroll
        for (int p = 0; p < 49; ++p) s = fmaf(xb[p], xb[p], s);
        sXsq[b] = s;
    }

    // ---------- P0b: H1 = ELU(bits @ Dmat), each wave its own m-tile ----------
    {
        int sg = chunk * 64 + w * 16 + lc;
        bf16x8 abits;
        #pragma unroll
        for (int j = 0; j < 8; ++j) {
            int k = quad * 8 + j;
            unsigned short u = 0;
            if (k < 14) u = ((sg >> (13 - k)) & 1) ? 0x3F80 : 0;
            else if (k == 14) u = 0x3F80;
            abits[j] = (short)u;
        }
        const bf16x8* dsw = (const bf16x8*)(wsb + WS_DSWZ_B) + (size_t)v * 18 * 64;
        for (int nt = 0; nt < 18; ++nt) {
            bf16x8 bfrag = dsw[nt * 64 + l];
            f32x4 d = {0.f, 0.f, 0.f, 0.f};
            d = __builtin_amdgcn_mfma_f32_16x16x32_bf16(abits, bfrag, d, 0, 0, 0);
            #pragma unroll
            for (int r = 0; r < 4; ++r)
                uni[(w * 16 + quad * 4 + r) * 288 + nt * 16 + lc] = f2bf(elu(d[r]));
        }
    }
    __syncthreads();

    // ---------- P1: conv2 GEMM  H2pre(64x416) = H1(64x288) @ W2eff ----------
    int ncnt = (w < 2) ? 7 : 6;
    int n0 = (w < 2) ? 7 * w : 14 + 6 * (w - 2);
    f32x4 acc[4][7];
    #pragma unroll
    for (int mt = 0; mt < 4; ++mt)
        #pragma unroll
        for (int j = 0; j < 7; ++j)
            acc[mt][j] = (f32x4){0.f, 0.f, 0.f, 0.f};
    {
        const bf16x8* w2f = (const bf16x8*)(wsb + WS_W2SWZ_B) + (size_t)v * 9 * 26 * 64;
        for (int kt = 0; kt < 9; ++kt) {
            bf16x8 a[4];
            #pragma unroll
            for (int mt = 0; mt < 4; ++mt)
                a[mt] = *(const bf16x8*)&uni[(mt * 16 + lc) * 288 + kt * 32 + quad * 8];
            bf16x8 bfr[7];
            #pragma unroll
            for (int j = 0; j < 7; ++j)
                if (j < ncnt) bfr[j] = w2f[(kt * 26 + n0 + j) * 64 + l];
            #pragma unroll
            for (int j = 0; j < 7; ++j)
                if (j < ncnt)
                    #pragma unroll
                    for (int mt = 0; mt < 4; ++mt)
                        acc[mt][j] = __builtin_amdgcn_mfma_f32_16x16x32_bf16(a[mt], bfr[j], acc[mt][j], 0, 0, 0);
        }
    }
    __syncthreads();   // all H1 reads done before uni is reused as sH2

    // X A-frags for P4, built in registers (loads overlap P2's VALU work)
    bf16x8 xf[2][2];
    #pragma unroll
    for (int mt = 0; mt < 2; ++mt)
        #pragma unroll
        for (int kt = 0; kt < 2; ++kt) {
            int b = mt * 16 + lc;
            #pragma unroll
            for (int j = 0; j < 8; ++j) {
                int p = kt * 32 + quad * 8 + j;
                unsigned short u = 0;
                if (p < 49) u = f2bf(x[(size_t)(b * 3 + v) * 49 + p]);
                xf[mt][kt][j] = (short)u;
            }
        }

    // ---------- P2: bias + ELU + bf16 -> sH2[s][416] ----------
    #pragma unroll
    for (int j = 0; j < 7; ++j) {
        if (j < ncnt) {
            int nt = n0 + j;
            int n = nt * 16 + lc;
            #pragma unroll
            for (int mt = 0; mt < 4; ++mt) {
                #pragma unroll
                for (int r = 0; r < 4; ++r) {
                    float val = 0.f;
                    if (n < 400) {
                        int o = n / 25;
                        val = elu(acc[mt][j][r] + sB2[o]);
                    }
                    uni[(mt * 16 + quad * 4 + r) * 416 + n] = f2bf(val);
                }
            }
        }
    }
    __syncthreads();

    // ---------- P3: conv3 GEMM  m(64x64) = H2(64x416) @ W3eff ----------
    f32x4 acc2[4];
    #pragma unroll
    for (int mt = 0; mt < 4; ++mt) acc2[mt] = (f32x4){0.f, 0.f, 0.f, 0.f};
    {
        const bf16x8* w3f = (const bf16x8*)(wsb + WS_W3SWZ_B) + (size_t)v * 13 * 4 * 64;
        for (int kt = 0; kt < 13; ++kt) {
            bf16x8 a[4];
            #pragma unroll
            for (int mt = 0; mt < 4; ++mt)
                a[mt] = *(const bf16x8*)&uni[(mt * 16 + lc) * 416 + kt * 32 + quad * 8];
            bf16x8 bfr = w3f[(kt * 4 + w) * 64 + l];
            #pragma unroll
            for (int mt = 0; mt < 4; ++mt)
                acc2[mt] = __builtin_amdgcn_mfma_f32_16x16x32_bf16(a[mt], bfr, acc2[mt], 0, 0, 0);
        }
    }
    // epilogue: means, ||m||^2, stash m for cross-term
    float b3v = b3p[v];
    float mvals[4][4];
    int p = w * 16 + lc;
    #pragma unroll
    for (int mt = 0; mt < 4; ++mt) {
        #pragma unroll
        for (int r = 0; r < 4; ++r) {
            float m = (p < 49) ? (acc2[mt][r] + b3v) : 0.f;
            mvals[mt][r] = m;
            float sq = m * m;
            sq += __shfl_xor(sq, 1, 64);
            sq += __shfl_xor(sq, 2, 64);
            sq += __shfl_xor(sq, 4, 64);
            sq += __shfl_xor(sq, 8, 64);
            if (lc == 0) atomicAdd(&sMsq[mt * 16 + quad * 4 + r], sq);
        }
    }
    __syncthreads();   // conv3 reads of uni done before reuse as sM
    #pragma unroll
    for (int mt = 0; mt < 4; ++mt)
        #pragma unroll
        for (int r = 0; r < 4; ++r)
            uni[(mt * 16 + quad * 4 + r) * 72 + p] = f2bf(mvals[mt][r]);
    __syncthreads();

    // ---------- P4: cross = X(32x64p) @ M^T(64p x 64s), then combine & store ----------
    f32x4 acc3[2];
    acc3[0] = (f32x4){0.f, 0.f, 0.f, 0.f};
    acc3[1] = (f32x4){0.f, 0.f, 0.f, 0.f};
    #pragma unroll
    for (int kt = 0; kt < 2; ++kt) {
        bf16x8 bm = *(const bf16x8*)&uni[(w * 16 + lc) * 72 + kt * 32 + quad * 8];
        #pragma unroll
        for (int mt = 0; mt < 2; ++mt)
            acc3[mt] = __builtin_amdgcn_mfma_f32_16x16x32_bf16(xf[mt][kt], bm, acc3[mt], 0, 0, 0);
    }
    {
        int s = w * 16 + lc;
        float msq = sMsq[s];
        size_t kidx = (size_t)(chunk * 64 + s) * 3 + v;
        #pragma unroll
        for (int mt = 0; mt < 2; ++mt) {
            int bbase = mt * 16 + quad * 4;
            #pragma unroll
            for (int r = 0; r < 4; ++r) {
                int b = bbase + r;
                float val = acc3[mt][r] - 0.5f * (msq + sXsq[b]);
                out[(size_t)b * (KSTATES * 3) + kidx] = val;
            }
        }
    }
}

extern "C" void kernel_launch(void* const* d_in, const int* in_sizes, int n_in,
                              void* d_out, int out_size, void* d_ws, size_t ws_size,
                              hipStream_t stream) {
    const float* x    = (const float*)d_in[0];   // (32,3,7,7)
    const float* emb  = (const float*)d_in[1];   // (14,2,32)
    const float* linw = (const float*)d_in[2];   // (3,448,64)
    const float* linb = (const float*)d_in[3];   // (3,64)
    const float* w1   = (const float*)d_in[4];   // (3,64,32,3,3)
    const float* b1   = (const float*)d_in[5];   // (3,32)
    const float* w2   = (const float*)d_in[6];   // (3,32,16,3,3)
    const float* b2   = (const float*)d_in[7];   // (3,16)
    const float* w3   = (const float*)d_in[8];   // (3,16,1,3,3)
    const float* b3   = (const float*)d_in[9];   // (3,1)
    float* out = (float*)d_out;
    float* ws = (float*)d_ws;

    preA_kernel<<<249, 256, 0, stream>>>(emb, linw, w2, w3, ws);
    preB_kernel<<<51, 256, 0, stream>>>(linb, b1, w1, ws, ws);
    emission_main<<<768, 256, 0, stream>>>(x, b2, b3, ws, out);
}

// Round 4
// 121.305 us; speedup vs baseline: 3.3862x; 1.1510x over previous
//
#include <hip/hip_runtime.h>
#include <math.h>

#define NVARS 14
#define EDIM 32
#define VMIX 3
#define KSTATES 16384
#define BATCH 32

// ws layout:
//   T: [V][NV][2][64] fp32   float offset 0       (5376 floats)
// bf16 swizzled-fragment regions (byte offsets):
#define WS_DSWZ_B  32768                       // [V][18][64][8] bf16 = 55296 B
#define WS_W2SWZ_B (WS_DSWZ_B + 55296)         // [V][9][26][64][8] = 718848 B
#define WS_W3SWZ_B (WS_W2SWZ_B + 718848)       // [V][13][4][64][8] = 79872 B

// LDS strides (shorts). 296 = 148dw (148%32=20, odd*4 -> conflict-free b128)
// 424 = 212dw (212%32=20). 72 = 36dw (36%32=4).
#define H1S 296
#define H2S 424
#define MS  72

typedef __attribute__((ext_vector_type(8))) short bf16x8;
typedef __attribute__((ext_vector_type(4))) float f32x4;

static __device__ inline unsigned short f2bf(float f) {
    unsigned u = __float_as_uint(f);
    u += 0x7FFFu + ((u >> 16) & 1u);   // RNE
    return (unsigned short)(u >> 16);
}
static __device__ inline float elu(float x) {
    return x > 0.f ? x : (__expf(x) - 1.f);
}

// ---------------- preA: T table + zero Dmat region + w2/w3 frag swizzles ----------------
__global__ __launch_bounds__(256) void preA_kernel(const float* __restrict__ emb,
                                                   const float* __restrict__ lin_w,
                                                   const float* __restrict__ w2,
                                                   const float* __restrict__ w3,
                                                   float* __restrict__ ws) {
    int t = blockIdx.x * 256 + threadIdx.x;   // 63744 total
    char* wsb = (char*)ws;
    if (t < 5376) {
        int vnc = t >> 6;
        int i = t & 63;
        int v = vnc / 28;
        int rem = vnc % 28;
        int n = rem >> 1;
        int c = rem & 1;
        const float* e = emb + (n * 2 + c) * EDIM;
        const float* lw = lin_w + ((size_t)v * 448 + n * 32) * 64 + i;
        float acc = 0.f;
        #pragma unroll
        for (int eidx = 0; eidx < 32; ++eidx)
            acc = fmaf(e[eidx], lw[eidx * 64], acc);
        ws[t] = acc;
        return;
    }
    int g = t - 5376;
    if (g >= 58368) return;
    bf16x8 o8;
    if (g < 3456) {
        #pragma unroll
        for (int j = 0; j < 8; ++j) o8[j] = 0;   // Dmat region: zero (preB fills k<15)
    } else if (g < 48384) {
        int h = g - 3456;
        int v = h / 14976;
        int r = h % 14976;
        int kt = r / 1664;
        int r2 = r % 1664;
        int nt = r2 / 64, l = r2 % 64;
        int n = nt * 16 + (l & 15);
        int kbase = kt * 32 + ((l >> 4) & 3) * 8;
        #pragma unroll
        for (int j = 0; j < 8; ++j) {
            int k = kbase + j;           // k < 288
            float val = 0.f;
            if (n < 400) {
                int i = k / 9, p = k % 9;
                int py = p / 3, px = p % 3;
                int o = n / 25, q = n % 25;
                int qy = q / 5, qx = q % 5;
                int ty = qy - py, tx = qx - px;
                if (ty >= 0 && ty < 3 && tx >= 0 && tx < 3)
                    val = w2[((size_t)(v * 32 + i) * 16 + o) * 9 + ty * 3 + tx];
            }
            o8[j] = (short)f2bf(val);
        }
    } else {
        int h = g - 48384;
        int v = h / 3328;
        int r = h % 3328;
        int kt = r / 256;
        int r2 = r % 256;
        int nt = r2 / 64, l = r2 % 64;
        int n = nt * 16 + (l & 15);      // output pixel 0..48 (else pad)
        int kbase = kt * 32 + ((l >> 4) & 3) * 8;
        #pragma unroll
        for (int j = 0; j < 8; ++j) {
            int k = kbase + j;
            float val = 0.f;
            if (k < 400 && n < 49) {
                int o = k / 25, q = k % 25;
                int qy = q / 5, qx = q % 5;
                int py = n / 7, px = n % 7;
                int ty = py - qy, tx = px - qx;
                if (ty >= 0 && ty < 3 && tx >= 0 && tx < 3)
                    val = w3[(size_t)(v * 16 + o) * 9 + ty * 3 + tx];
            }
            o8[j] = (short)f2bf(val);
        }
    }
    *(bf16x8*)(wsb + WS_DSWZ_B + (size_t)g * 16) = o8;
}

// ---------------- preB: Dmat bf16 frags directly (delta rows k<14, base row k=14) ----------------
__global__ __launch_bounds__(256) void preB_kernel(const float* __restrict__ lin_b,
                                                   const float* __restrict__ b1,
                                                   const float* __restrict__ w1,
                                                   const float* __restrict__ ws_ro,
                                                   float* __restrict__ ws) {
    int t = blockIdx.x * 256 + threadIdx.x;
    if (t >= VMIX * 15 * 288) return;     // 12960
    int v = t / (15 * 288);
    int r = t % (15 * 288);
    int k = r / 288;
    int n = r % 288;                      // lane-consecutive -> coalesced w1 column loads
    const float* w1v = w1 + (size_t)v * 64 * 288;
    const float* Tv = ws_ro + (size_t)v * NVARS * 2 * 64;
    float val;
    if (k < 14) {
        const float* T0 = Tv + (k * 2 + 0) * 64;
        const float* T1 = Tv + (k * 2 + 1) * 64;
        float acc = 0.f;
        for (int i = 0; i < 64; ++i)
            acc = fmaf(T1[i] - T0[i], w1v[i * 288 + n], acc);
        val = acc;
    } else {
        const float* lbv = lin_b + v * 64;
        float acc = b1[v * 32 + n / 9];
        for (int i = 0; i < 64; ++i) {
            float u = lbv[i];
            #pragma unroll
            for (int n2 = 0; n2 < 14; ++n2)
                u += Tv[(n2 * 2 + 0) * 64 + i];
            acc = fmaf(u, w1v[i * 288 + n], acc);
        }
        val = acc;
    }
    int nt = n >> 4;
    int l = (n & 15) | ((k >> 3) << 4);
    int j = k & 7;
    unsigned short* dst = (unsigned short*)((char*)ws + WS_DSWZ_B);
    dst[((size_t)(v * 18 + nt) * 64 + l) * 8 + j] = f2bf(val);
}

// ---------------- main: MFMA decoder + distance (512 threads, 8 waves) ----------------
__global__ __launch_bounds__(512, 4) void emission_main(const float* __restrict__ x,
                                                        const float* __restrict__ b2,
                                                        const float* __restrict__ b3p,
                                                        const float* __restrict__ ws,
                                                        float* __restrict__ out) {
    int bid = blockIdx.x;
    // XCD swizzle: v-trio for a chunk shares bid%8 and is temporally close.
    int group = bid / 24;
    int j24 = bid % 24;
    int v = j24 >> 3;
    int chunk = group * 8 + (j24 & 7);    // states [chunk*64, chunk*64+64)
    int tid = threadIdx.x;
    int w = tid >> 6;           // wave 0..7
    int l = tid & 63;
    int quad = l >> 4;
    int lc = l & 15;
    const char* wsb = (const char*)ws;

    // union: sH1 (64 x H1S shorts = 37888B) -> sH2 (64 x H2S = 54272B) -> sM (64 x MS)
    __shared__ __align__(16) unsigned short uni[64 * H2S];
    __shared__ float sMsq[64];
    __shared__ float sXsq[32];
    __shared__ float sB2[16];

    // ---------- P0: small LDS prep ----------
    if (tid < 16) sB2[tid] = b2[v * 16 + tid];
    if (tid < 64) sMsq[tid] = 0.f;
    if (tid >= 64 && tid < 96) {
        int b = tid - 64;
        const float* xb = x + (size_t)(b * 3 + v) * 49;
        float s = 0.f;
        #pragma unroll
        for (int p = 0; p < 49; ++p) s = fmaf(xb[p], xb[p], s);
        sXsq[b] = s;
    }

    int mt0 = w & 3;            // this wave's m-tile for P0b/P3
    // ---------- P0b: H1 = ELU(bits @ Dmat); wave (mt0, nh = w>>2) ----------
    {
        int nh = w >> 2;
        int sg = chunk * 64 + mt0 * 16 + lc;
        bf16x8 abits;
        #pragma unroll
        for (int j = 0; j < 8; ++j) {
            int k = quad * 8 + j;
            unsigned short u = 0;
            if (k < 14) u = ((sg >> (13 - k)) & 1) ? 0x3F80 : 0;
            else if (k == 14) u = 0x3F80;
            abits[j] = (short)u;
        }
        const bf16x8* dsw = (const bf16x8*)(wsb + WS_DSWZ_B) + (size_t)v * 18 * 64;
        for (int i = 0; i < 9; ++i) {
            int nt = nh * 9 + i;
            bf16x8 bfrag = dsw[nt * 64 + l];
            f32x4 d = {0.f, 0.f, 0.f, 0.f};
            d = __builtin_amdgcn_mfma_f32_16x16x32_bf16(abits, bfrag, d, 0, 0, 0);
            #pragma unroll
            for (int r = 0; r < 4; ++r)
                uni[(mt0 * 16 + quad * 4 + r) * H1S + nt * 16 + lc] = f2bf(elu(d[r]));
        }
    }
    __syncthreads();

    // ---------- P1: conv2 GEMM  H2pre(64x416) = H1(64x288) @ W2eff ----------
    int ncnt = (w < 2) ? 4 : 3;
    int n0 = (w < 2) ? 4 * w : 8 + 3 * (w - 2);   // 26 n-tiles over 8 waves
    f32x4 acc[4][4];
    #pragma unroll
    for (int mt = 0; mt < 4; ++mt)
        #pragma unroll
        for (int j = 0; j < 4; ++j)
            acc[mt][j] = (f32x4){0.f, 0.f, 0.f, 0.f};
    {
        const bf16x8* w2f = (const bf16x8*)(wsb + WS_W2SWZ_B) + (size_t)v * 9 * 26 * 64;
        for (int kt = 0; kt < 9; ++kt) {
            bf16x8 a[4];
            #pragma unroll
            for (int mt = 0; mt < 4; ++mt)
                a[mt] = *(const bf16x8*)&uni[(mt * 16 + lc) * H1S + kt * 32 + quad * 8];
            bf16x8 bfr[4];
            #pragma unroll
            for (int j = 0; j < 4; ++j)
                if (j < ncnt) bfr[j] = w2f[(kt * 26 + n0 + j) * 64 + l];
            #pragma unroll
            for (int j = 0; j < 4; ++j)
                if (j < ncnt)
                    #pragma unroll
                    for (int mt = 0; mt < 4; ++mt)
                        acc[mt][j] = __builtin_amdgcn_mfma_f32_16x16x32_bf16(a[mt], bfr[j], acc[mt][j], 0, 0, 0);
        }
    }
    __syncthreads();   // all H1 reads done before uni is reused as sH2

    // X A-frags for P4 (this wave's b-tile bt = w>>2), built in registers
    bf16x8 xf[2];
    {
        int bt = w >> 2;
        #pragma unroll
        for (int kt = 0; kt < 2; ++kt) {
            int b = bt * 16 + lc;
            #pragma unroll
            for (int j = 0; j < 8; ++j) {
                int p = kt * 32 + quad * 8 + j;
                unsigned short u = 0;
                if (p < 49) u = f2bf(x[(size_t)(b * 3 + v) * 49 + p]);
                xf[kt][j] = (short)u;
            }
        }
    }

    // ---------- P2: bias + ELU + bf16 -> sH2[s][H2S] ----------
    #pragma unroll
    for (int j = 0; j < 4; ++j) {
        if (j < ncnt) {
            int n = (n0 + j) * 16 + lc;
            #pragma unroll
            for (int mt = 0; mt < 4; ++mt) {
                #pragma unroll
                for (int r = 0; r < 4; ++r) {
                    float val = 0.f;
                    if (n < 400) {
                        int o = n / 25;
                        val = elu(acc[mt][j][r] + sB2[o]);
                    }
                    uni[(mt * 16 + quad * 4 + r) * H2S + n] = f2bf(val);
                }
            }
        }
    }
    __syncthreads();

    // ---------- P3: conv3 GEMM  m(64x64) = H2(64x416) @ W3eff ----------
    // wave: (mt0 = w&3, p-tiles {ph, ph+2}, ph = w>>2)
    int ph = w >> 2;
    f32x4 acc2[2];
    acc2[0] = (f32x4){0.f, 0.f, 0.f, 0.f};
    acc2[1] = (f32x4){0.f, 0.f, 0.f, 0.f};
    {
        const bf16x8* w3f = (const bf16x8*)(wsb + WS_W3SWZ_B) + (size_t)v * 13 * 4 * 64;
        for (int kt = 0; kt < 13; ++kt) {
            bf16x8 a = *(const bf16x8*)&uni[(mt0 * 16 + lc) * H2S + kt * 32 + quad * 8];
            #pragma unroll
            for (int c = 0; c < 2; ++c) {
                int pt = ph + 2 * c;
                bf16x8 bfr = w3f[(kt * 4 + pt) * 64 + l];
                acc2[c] = __builtin_amdgcn_mfma_f32_16x16x32_bf16(a, bfr, acc2[c], 0, 0, 0);
            }
        }
    }
    // epilogue: means, ||m||^2
    float b3v = b3p[v];
    float mv[2][4];
    #pragma unroll
    for (int c = 0; c < 2; ++c) {
        int p = (ph + 2 * c) * 16 + lc;
        #pragma unroll
        for (int r = 0; r < 4; ++r)
            mv[c][r] = (p < 49) ? (acc2[c][r] + b3v) : 0.f;
    }
    #pragma unroll
    for (int r = 0; r < 4; ++r) {
        float sq = mv[0][r] * mv[0][r] + mv[1][r] * mv[1][r];
        sq += __shfl_xor(sq, 1, 64);
        sq += __shfl_xor(sq, 2, 64);
        sq += __shfl_xor(sq, 4, 64);
        sq += __shfl_xor(sq, 8, 64);
        if (lc == 0) atomicAdd(&sMsq[mt0 * 16 + quad * 4 + r], sq);
    }
    __syncthreads();   // conv3 reads of uni done before reuse as sM
    #pragma unroll
    for (int c = 0; c < 2; ++c) {
        int p = (ph + 2 * c) * 16 + lc;
        #pragma unroll
        for (int r = 0; r < 4; ++r)
            uni[(mt0 * 16 + quad * 4 + r) * MS + p] = f2bf(mv[c][r]);
    }
    __syncthreads();

    // ---------- P4: cross = X(32x64p) @ M^T, wave: (st = w&3, bt = w>>2) ----------
    {
        int st = w & 3, bt = w >> 2;
        f32x4 acc3 = {0.f, 0.f, 0.f, 0.f};
        #pragma unroll
        for (int kt = 0; kt < 2; ++kt) {
            bf16x8 bm = *(const bf16x8*)&uni[(st * 16 + lc) * MS + kt * 32 + quad * 8];
            acc3 = __builtin_amdgcn_mfma_f32_16x16x32_bf16(xf[kt], bm, acc3, 0, 0, 0);
        }
        int s = st * 16 + lc;
        float msq = sMsq[s];
        size_t kidx = (size_t)(chunk * 64 + s) * 3 + v;
        #pragma unroll
        for (int r = 0; r < 4; ++r) {
            int b = bt * 16 + quad * 4 + r;
            out[(size_t)b * (KSTATES * 3) + kidx] = acc3[r] - 0.5f * (msq + sXsq[b]);
        }
    }
}

extern "C" void kernel_launch(void* const* d_in, const int* in_sizes, int n_in,
                              void* d_out, int out_size, void* d_ws, size_t ws_size,
                              hipStream_t stream) {
    const float* x    = (const float*)d_in[0];   // (32,3,7,7)
    const float* emb  = (const float*)d_in[1];   // (14,2,32)
    const float* linw = (const float*)d_in[2];   // (3,448,64)
    const float* linb = (const float*)d_in[3];   // (3,64)
    const float* w1   = (const float*)d_in[4];   // (3,64,32,3,3)
    const float* b1   = (const float*)d_in[5];   // (3,32)
    const float* w2   = (const float*)d_in[6];   // (3,32,16,3,3)
    const float* b2   = (const float*)d_in[7];   // (3,16)
    const float* w3   = (const float*)d_in[8];   // (3,16,1,3,3)
    const float* b3   = (const float*)d_in[9];   // (3,1)
    float* out = (float*)d_out;
    float* ws = (float*)d_ws;

    preA_kernel<<<249, 256, 0, stream>>>(emb, linw, w2, w3, ws);
    preB_kernel<<<51, 256, 0, stream>>>(linb, b1, w1, ws, ws);
    emission_main<<<768, 512, 0, stream>>>(x, b2, b3, ws, out);
}